// Round 10
// baseline (406.468 us; speedup 1.0000x reference)
//
#include <hip/hip_runtime.h>
#include <hip/hip_bf16.h>

#define IN_CH 128
#define HID_CH 64
#define OUT_CH 32
#define EPB 2048  // edges per block in deg/scatter

typedef unsigned short ushort_t;
typedef __attribute__((ext_vector_type(8))) short short8;
typedef __attribute__((ext_vector_type(4))) float float4v;
typedef __attribute__((ext_vector_type(4))) float fx4;
typedef __attribute__((ext_vector_type(4))) unsigned ux4;
using half8 = __attribute__((ext_vector_type(8))) _Float16;

static __device__ __forceinline__ ushort_t f2bf(float f) {
    unsigned u = __float_as_uint(f);
    unsigned r = (u + 0x7fff + ((u >> 16) & 1)) >> 16;  // RNE
    return (ushort_t)r;
}
static __device__ __forceinline__ float bf_lo(unsigned u) { return __uint_as_float(u << 16); }
static __device__ __forceinline__ float bf_hi(unsigned u) { return __uint_as_float(u & 0xffff0000u); }

static __device__ __forceinline__ unsigned f2h2(float lo, float hi) {  // RNE f32->f16 pair, packed
    union { _Float16 h[2]; unsigned u; } v;
    v.h[0] = (_Float16)lo;
    v.h[1] = (_Float16)hi;
    return v.u;
}
static __device__ __forceinline__ unsigned pkh(float a, float b) {  // RTZ packed cvt (fast path)
    auto p = __builtin_amdgcn_cvt_pkrtz(a, b);
    union { decltype(p) h; unsigned u; } v;
    v.h = p;
    return v.u;
}

// ---------------- deg: direct global-atomic in-degree histogram (+ prepW in 5 trailing blocks) ----------------
// cursor[] doubles as deg[]: 0.4MB, L2-resident; random-address atomics run at L2-channel rate.

__global__ __launch_bounds__(256) void k_deg(const int* __restrict__ dst,
                                             int* __restrict__ cursor,
                                             int E, int DB,
                                             const float* __restrict__ W1,
                                             const float* __restrict__ W2,
                                             unsigned* __restrict__ wsW) {
    const int tid = threadIdx.x;
    if (blockIdx.x >= DB) {  // prepW blocks
        int s = (blockIdx.x - DB) * 256 + tid;  // 0..1279
        if (s < 1024) {                          // W1 -> bf16 b-frags
            int lane = s & 63;
            int nt = (s >> 6) & 3;
            int kc = s >> 8;
            int c = nt * 16 + (lane & 15);
            int k0 = kc * 32 + (lane >> 4) * 8;
            unsigned o[4];
#pragma unroll
            for (int d = 0; d < 4; ++d) {
                unsigned lo = f2bf(W1[(k0 + 2 * d) * 64 + c]);
                unsigned hi = f2bf(W1[(k0 + 2 * d + 1) * 64 + c]);
                o[d] = lo | (hi << 16);
            }
            ((uint4*)wsW)[s] = make_uint4(o[0], o[1], o[2], o[3]);
        } else {  // W2 -> f16 b-frags: frag f = kt*2+ct
            int q = s - 1024;  // 0..255
            int lane = q & 63;
            int f = q >> 6;
            int c = (f & 1) * 16 + (lane & 15);
            int k0 = (f >> 1) * 32 + (lane >> 4) * 8;
            unsigned o[4];
#pragma unroll
            for (int d = 0; d < 4; ++d)
                o[d] = f2h2(W2[(k0 + 2 * d) * 32 + c], W2[(k0 + 2 * d + 1) * 32 + c]);
            ((uint4*)wsW)[1024 + q] = make_uint4(o[0], o[1], o[2], o[3]);
        }
        return;
    }

    const int e0 = blockIdx.x * EPB;
#pragma unroll
    for (int j = 0; j < 8; ++j) {
        int e = e0 + j * 256 + tid;
        if (e < E) atomicAdd(&cursor[__builtin_nontemporal_load(dst + e)], 1);
    }
}

// ---------------- scanA: per-2048-row block sums of deg ----------------

__global__ __launch_bounds__(256) void k_scanA(const int* __restrict__ cursor,
                                               int* __restrict__ bsum, int N) {
    __shared__ int ls[256];
    const int tid = threadIdx.x;
    const int base = blockIdx.x * 2048;
    int s = 0;
#pragma unroll
    for (int i = 0; i < 8; ++i) {
        int r = base + i * 256 + tid;
        s += (r < N) ? cursor[r] : 0;
    }
    ls[tid] = s;
    __syncthreads();
    for (int off = 128; off; off >>= 1) {
        if (tid < off) ls[tid] += ls[tid + off];
        __syncthreads();
    }
    if (tid == 0) bsum[blockIdx.x] = ls[0];
}

// ---------------- scanB: exclusive scan -> rowptr, cursor (scatter base), dis ----------------
// Also writes rowptr[N]=E and zeroes the h1 half pad rows.

__global__ __launch_bounds__(256) void k_scanB(int* __restrict__ cursor,
                                               const int* __restrict__ bsum,
                                               int* __restrict__ rowptr,
                                               float* __restrict__ dis,
                                               unsigned* __restrict__ h1d,
                                               int N, int E) {
    __shared__ int ldeg[2048];
    __shared__ int ls[256];
    __shared__ int gbase_s;
    const int tid = threadIdx.x, b = blockIdx.x;

    if (b == 0 && tid < 32)  // h1 half hf pad row: 32 bf16 = 16 dwords
        h1d[(long long)(tid >> 4) * (N + 1) * 16 + (long long)N * 16 + (tid & 15)] = 0;
    if (b == 0 && tid == 0) rowptr[N] = E;

    if (tid == 0) {
        int g = 0;
        for (int i = 0; i < b; ++i) g += bsum[i];  // <=48 serial adds
        gbase_s = g;
    }
    const int base = b * 2048;
#pragma unroll
    for (int i = 0; i < 8; ++i) {
        int r = base + i * 256 + tid;
        ldeg[i * 256 + tid] = (r < N) ? cursor[r] : 0;
    }
    __syncthreads();

    int loc[8];
    int s = 0;
#pragma unroll
    for (int i = 0; i < 8; ++i) {
        loc[i] = s;
        s += ldeg[tid * 8 + i];
    }
    ls[tid] = s;
    __syncthreads();
    for (int off = 1; off < 256; off <<= 1) {
        int val = (tid >= off) ? ls[tid - off] : 0;
        __syncthreads();
        ls[tid] += val;
        __syncthreads();
    }
    const int texcl = (tid ? ls[tid - 1] : 0) + gbase_s;
#pragma unroll
    for (int i = 0; i < 8; ++i) {
        int r = base + tid * 8 + i;
        if (r < N) {
            int start = texcl + loc[i];
            rowptr[r] = start;
            cursor[r] = start;  // scatter cursor (deg consumed; safe: all reads done pre-barrier)
            dis[r] = rsqrtf((float)(ldeg[tid * 8 + i] + 1));  // +1 self-loop
        }
    }
}

// ---------------- scatter: direct CSR fill (unique slot per edge, no overflow possible) ----------------
// Writes for one dst row land on consecutive col positions -> same line, L2-coalesced.

__global__ __launch_bounds__(256) void k_scatter(const int* __restrict__ src,
                                                 const int* __restrict__ dst,
                                                 int* __restrict__ cursor,
                                                 int* __restrict__ col, int E) {
    const int tid = threadIdx.x;
    const int e0 = blockIdx.x * EPB;
#pragma unroll
    for (int j = 0; j < 8; ++j) {
        int e = e0 + j * 256 + tid;
        if (e < E) {
            int d = __builtin_nontemporal_load(dst + e);
            int s = __builtin_nontemporal_load(src + e);
            int pos = atomicAdd(&cursor[d], 1);
            col[pos] = s;
        }
    }
}

// ---------------- L1 matmul via MFMA; HALF-2 output: half hf = channels 32hf..32hf+31 ----------------
// h1'[hf][row][32ch bf16 = 64B = one cache line], pre-scaled by dis[row].

__global__ __launch_bounds__(256) void k_mm1(const float* __restrict__ X,
                                             const unsigned* __restrict__ wsW,
                                             const float* __restrict__ dis,
                                             ushort_t* __restrict__ H, int N) {
    const int tid = threadIdx.x;
    const int wv = tid >> 6, lane = tid & 63;
    const int quad = lane >> 4, n16 = lane & 15;
    const int rowbase = blockIdx.x * 64 + wv * 16;
    const int myrow = rowbase + n16;
    const bool rok = (myrow < N);

    float4v acc0 = {}, acc1 = {}, acc2 = {}, acc3 = {};

#pragma unroll
    for (int kc = 0; kc < 4; ++kc) {
        float4 xa = make_float4(0.f, 0.f, 0.f, 0.f), xb = xa;
        if (rok) {
            const float4* p = (const float4*)(X + (long long)myrow * 128 + kc * 32 + quad * 8);
            xa = p[0];
            xb = p[1];
        }
        unsigned pk[4];
        pk[0] = (unsigned)f2bf(xa.x) | ((unsigned)f2bf(xa.y) << 16);
        pk[1] = (unsigned)f2bf(xa.z) | ((unsigned)f2bf(xa.w) << 16);
        pk[2] = (unsigned)f2bf(xb.x) | ((unsigned)f2bf(xb.y) << 16);
        pk[3] = (unsigned)f2bf(xb.z) | ((unsigned)f2bf(xb.w) << 16);
        short8 a;
        a[0] = (short)(pk[0] & 0xffff); a[1] = (short)(pk[0] >> 16);
        a[2] = (short)(pk[1] & 0xffff); a[3] = (short)(pk[1] >> 16);
        a[4] = (short)(pk[2] & 0xffff); a[5] = (short)(pk[2] >> 16);
        a[6] = (short)(pk[3] & 0xffff); a[7] = (short)(pk[3] >> 16);

        const short8* wb = (const short8*)wsW;
        short8 b0 = wb[(kc * 4 + 0) * 64 + lane];
        short8 b1 = wb[(kc * 4 + 1) * 64 + lane];
        short8 b2 = wb[(kc * 4 + 2) * 64 + lane];
        short8 b3 = wb[(kc * 4 + 3) * 64 + lane];

        acc0 = __builtin_amdgcn_mfma_f32_16x16x32_bf16(a, b0, acc0, 0, 0, 0);
        acc1 = __builtin_amdgcn_mfma_f32_16x16x32_bf16(a, b1, acc1, 0, 0, 0);
        acc2 = __builtin_amdgcn_mfma_f32_16x16x32_bf16(a, b2, acc2, 0, 0, 0);
        acc3 = __builtin_amdgcn_mfma_f32_16x16x32_bf16(a, b3, acc3, 0, 0, 0);
    }

    const long long hb1 = (long long)(N + 1) * 32;  // half-1 base (ushort units)
#pragma unroll
    for (int i = 0; i < 4; ++i) {
        int row = rowbase + quad * 4 + i;
        if (row < N) {
            float dr = dis[row];
            long long o = (long long)row * 32 + n16;
            H[o]            = f2bf(dr * acc0[i]);  // ch n16       (half 0)
            H[o + 16]       = f2bf(dr * acc1[i]);  // ch 16+n16    (half 0)
            H[hb1 + o]      = f2bf(dr * acc2[i]);  // ch 32+n16    (half 1)
            H[hb1 + o + 16] = f2bf(dr * acc3[i]);  // ch 48+n16    (half 1)
        }
    }
}

// ---------------- gather1h: layer-1 aggregation, channel-HALF per XCD-quad (r7, verified) ----------------

__global__ __launch_bounds__(256, 8) void k_gather1h(const unsigned* __restrict__ h,
                                                     const int* __restrict__ rowptr,
                                                     const int* __restrict__ col,
                                                     const float* __restrict__ dis,
                                                     const float* __restrict__ b1,
                                                     unsigned* __restrict__ z, int N) {
    const int tid = threadIdx.x;
    const int wv = tid >> 6, lane = tid & 63;
    const int t = lane & 3, g = lane >> 2;  // 16 groups x 4 lanes
    const int xcd = blockIdx.x & 7;
    const int hf = xcd >> 2;
    const int pb = ((blockIdx.x >> 3) << 2) | (xcd & 3);  // per-half block id
    const int nwh = ((gridDim.x >> 3) << 2) * 4;          // waves per half

    const uint4* h4 = (const uint4*)h + (long long)hf * (N + 1) * 4;  // 64B rows
    ux4* zp = (ux4*)z + (long long)hf * (N + 1) * 4;
    const float4 ba = ((const float4*)b1)[hf * 8 + t * 2];      // ch 32hf+8t..+3
    const float4 bb = ((const float4*)b1)[hf * 8 + t * 2 + 1];  // ch 32hf+8t+4..+7

    const int NBR = (N + 15) >> 4;

    for (int ri = pb * 4 + wv; ri < NBR; ri += nwh) {
        const int r0 = ri * 16;
        int rp_l = rowptr[min(r0 + min(lane, 16), N)];
        float dis_l = (lane < 16 && r0 + lane < N) ? dis[r0 + lane] : 0.f;
        const int sg = __shfl(rp_l, g);
        const int dg = __shfl(rp_l, g + 1) - sg;
        const float drg = __shfl(dis_l, g);
        const int rme = min(r0 + g, N);

        int mc0 = N, mc1 = N, mc2 = N, mc3 = N, mc4 = N, mc5 = N;
        if (t < dg)      mc0 = __builtin_nontemporal_load(col + sg + t);
        if (4 + t < dg)  mc1 = __builtin_nontemporal_load(col + sg + 4 + t);
        if (8 + t < dg)  mc2 = __builtin_nontemporal_load(col + sg + 8 + t);
        if (12 + t < dg) mc3 = __builtin_nontemporal_load(col + sg + 12 + t);
        if (16 + t < dg) mc4 = __builtin_nontemporal_load(col + sg + 16 + t);
        if (20 + t < dg) mc5 = __builtin_nontemporal_load(col + sg + 20 + t);

        uint4 us = h4[(long long)rme * 4 + t];  // self-loop slice (pre-scaled)
        float2 p0 = make_float2(bf_lo(us.x), bf_hi(us.x));
        float2 p1 = make_float2(bf_lo(us.y), bf_hi(us.y));
        float2 p2 = make_float2(bf_lo(us.z), bf_hi(us.z));
        float2 p3 = make_float2(bf_lo(us.w), bf_hi(us.w));

#define GATH(MC, J)                                                   \
    {                                                                 \
        int s_ = __shfl((MC), (g << 2) + (J));                        \
        uint4 uu = h4[(long long)s_ * 4 + t];                         \
        p0 += make_float2(bf_lo(uu.x), bf_hi(uu.x));                  \
        p1 += make_float2(bf_lo(uu.y), bf_hi(uu.y));                  \
        p2 += make_float2(bf_lo(uu.z), bf_hi(uu.z));                  \
        p3 += make_float2(bf_lo(uu.w), bf_hi(uu.w));                  \
    }
#pragma unroll
        for (int j = 0; j < 4; ++j) GATH(mc0, j)
#pragma unroll
        for (int j = 0; j < 4; ++j) GATH(mc1, j)
#pragma unroll
        for (int j = 0; j < 4; ++j) GATH(mc2, j)
#pragma unroll
        for (int j = 0; j < 4; ++j) GATH(mc3, j)
#pragma unroll
        for (int j = 0; j < 4; ++j) GATH(mc4, j)
#pragma unroll
        for (int j = 0; j < 4; ++j) GATH(mc5, j)
        if (__any(dg > 24)) {
            int mc6 = N, mc7 = N;
            if (24 + t < dg) mc6 = __builtin_nontemporal_load(col + sg + 24 + t);
            if (28 + t < dg) mc7 = __builtin_nontemporal_load(col + sg + 28 + t);
#pragma unroll
            for (int j = 0; j < 4; ++j) GATH(mc6, j)
#pragma unroll
            for (int j = 0; j < 4; ++j) GATH(mc7, j)
        }
        for (int u = 32;; ++u) {  // ultra-rare serial tail (broadcast col within group)
            bool act = u < dg;
            if (!__any(act)) break;
            if (act) {
                int s_ = col[sg + u];
                uint4 uu = h4[(long long)s_ * 4 + t];
                p0 += make_float2(bf_lo(uu.x), bf_hi(uu.x));
                p1 += make_float2(bf_lo(uu.y), bf_hi(uu.y));
                p2 += make_float2(bf_lo(uu.z), bf_hi(uu.z));
                p3 += make_float2(bf_lo(uu.w), bf_hi(uu.w));
            }
        }
#undef GATH

        if (r0 + g < N) {
            float z0 = fmaxf(fmaf(drg, p0.x, ba.x), 0.f);
            float z1 = fmaxf(fmaf(drg, p0.y, ba.y), 0.f);
            float z2 = fmaxf(fmaf(drg, p1.x, ba.z), 0.f);
            float z3 = fmaxf(fmaf(drg, p1.y, ba.w), 0.f);
            float z4 = fmaxf(fmaf(drg, p2.x, bb.x), 0.f);
            float z5 = fmaxf(fmaf(drg, p2.y, bb.y), 0.f);
            float z6 = fmaxf(fmaf(drg, p3.x, bb.z), 0.f);
            float z7 = fmaxf(fmaf(drg, p3.y, bb.w), 0.f);
            ux4 zo;
            zo.x = pkh(z0, z1);
            zo.y = pkh(z2, z3);
            zo.z = pkh(z4, z5);
            zo.w = pkh(z6, z7);
            __builtin_nontemporal_store(zo, zp + (long long)(r0 + g) * 4 + t);
        }
    }
}

// ---------------- mm2: h2' = dis[row]*(z @ W2); z from 2 f16 halves; h2 HALF-2 bf16 (r7) ----------------

__global__ __launch_bounds__(256) void k_mm2(const unsigned* __restrict__ z,
                                             const unsigned* __restrict__ wsW2,
                                             const float* __restrict__ dis,
                                             ushort_t* __restrict__ H2, int N) {
    const int tid = threadIdx.x;
    if (blockIdx.x == 0 && tid < 16)
        ((unsigned*)H2)[(long long)(tid >> 3) * (N + 1) * 8 + (long long)N * 8 + (tid & 7)] = 0;

    const int wv = tid >> 6, lane = tid & 63;
    const int n16 = lane & 15, kq = lane >> 4;
    const int rowbase = blockIdx.x * 64 + wv * 16;
    const int rz = min(rowbase + n16, N - 1);

    const uint4* z4 = (const uint4*)z;
    uint4 a0 = z4[(long long)rz * 4 + kq];                          // half0: ch 8kq..+7
    uint4 a1 = z4[(long long)(N + 1) * 4 + (long long)rz * 4 + kq]; // half1: ch 32+8kq..+7

    const half8* wfh = (const half8*)wsW2;
    const half8 bf00 = wfh[lane];
    const half8 bf01 = wfh[64 + lane];
    const half8 bf10 = wfh[128 + lane];
    const half8 bf11 = wfh[192 + lane];

    union U { uint4 u; half8 h; };
    U ua0, ua1;
    ua0.u = a0;
    ua1.u = a1;

    float4v c0 = {}, c1 = {};
    c0 = __builtin_amdgcn_mfma_f32_16x16x32_f16(ua0.h, bf00, c0, 0, 0, 0);
    c0 = __builtin_amdgcn_mfma_f32_16x16x32_f16(ua1.h, bf10, c0, 0, 0, 0);
    c1 = __builtin_amdgcn_mfma_f32_16x16x32_f16(ua0.h, bf01, c1, 0, 0, 0);
    c1 = __builtin_amdgcn_mfma_f32_16x16x32_f16(ua1.h, bf11, c1, 0, 0, 0);

    float dis_l = (lane < 16 && rowbase + lane < N) ? dis[rowbase + lane] : 0.f;
    const long long hb1 = (long long)(N + 1) * 16;
#pragma unroll
    for (int i = 0; i < 4; ++i) {
        int rr = rowbase + kq * 4 + i;  // C row = (lane>>4)*4 + reg
        float dr = __shfl(dis_l, kq * 4 + i);
        if (rr < N) {
            H2[(long long)rr * 16 + n16]       = f2bf(dr * c0[i]);  // half0: ch n16
            H2[hb1 + (long long)rr * 16 + n16] = f2bf(dr * c1[i]);  // half1: ch 16+n16
        }
    }
}

// ---------------- agg32h: final aggregation, channel-half per XCD-quad (r7, verified) ----------------

__global__ __launch_bounds__(256, 8) void k_agg32h(const unsigned* __restrict__ h2,
                                                   const int* __restrict__ rowptr,
                                                   const int* __restrict__ col,
                                                   const float* __restrict__ dis,
                                                   const float* __restrict__ b2,
                                                   float* __restrict__ out, int N) {
    const int tid = threadIdx.x;
    const int wv = tid >> 6, lane = tid & 63;
    const int t = lane & 3, g = lane >> 2;
    const int xcd = blockIdx.x & 7;
    const int hf = xcd >> 2;
    const int pb = ((blockIdx.x >> 3) << 2) | (xcd & 3);
    const int nwh = ((gridDim.x >> 3) << 2) * 4;

    const uint2* hw = (const uint2*)h2 + (long long)hf * (N + 1) * 4;  // 32B rows
    const float4 bq = ((const float4*)b2)[hf * 4 + t];  // ch 16hf+4t..+3

    const int NBR = (N + 15) >> 4;

    for (int ri = pb * 4 + wv; ri < NBR; ri += nwh) {
        const int r0 = ri * 16;
        int rp_l = rowptr[min(r0 + min(lane, 16), N)];
        float dis_l = (lane < 16 && r0 + lane < N) ? dis[r0 + lane] : 0.f;
        const int sg = __shfl(rp_l, g);
        const int dg = __shfl(rp_l, g + 1) - sg;
        const float drg = __shfl(dis_l, g);
        const int rme = min(r0 + g, N);

        int mc0 = N, mc1 = N, mc2 = N, mc3 = N, mc4 = N, mc5 = N;
        if (t < dg)      mc0 = __builtin_nontemporal_load(col + sg + t);
        if (4 + t < dg)  mc1 = __builtin_nontemporal_load(col + sg + 4 + t);
        if (8 + t < dg)  mc2 = __builtin_nontemporal_load(col + sg + 8 + t);
        if (12 + t < dg) mc3 = __builtin_nontemporal_load(col + sg + 12 + t);
        if (16 + t < dg) mc4 = __builtin_nontemporal_load(col + sg + 16 + t);
        if (20 + t < dg) mc5 = __builtin_nontemporal_load(col + sg + 20 + t);

        uint2 us = hw[(long long)rme * 4 + t];  // self-loop slice
        float2 p0 = make_float2(bf_lo(us.x), bf_hi(us.x));
        float2 p1 = make_float2(bf_lo(us.y), bf_hi(us.y));

#define GATH2(MC, J)                                                  \
    {                                                                 \
        int s_ = __shfl((MC), (g << 2) + (J));                        \
        uint2 uu = hw[(long long)s_ * 4 + t];                         \
        p0 += make_float2(bf_lo(uu.x), bf_hi(uu.x));                  \
        p1 += make_float2(bf_lo(uu.y), bf_hi(uu.y));                  \
    }
#pragma unroll
        for (int j = 0; j < 4; ++j) GATH2(mc0, j)
#pragma unroll
        for (int j = 0; j < 4; ++j) GATH2(mc1, j)
#pragma unroll
        for (int j = 0; j < 4; ++j) GATH2(mc2, j)
#pragma unroll
        for (int j = 0; j < 4; ++j) GATH2(mc3, j)
#pragma unroll
        for (int j = 0; j < 4; ++j) GATH2(mc4, j)
#pragma unroll
        for (int j = 0; j < 4; ++j) GATH2(mc5, j)
        if (__any(dg > 24)) {
            int mc6 = N, mc7 = N;
            if (24 + t < dg) mc6 = __builtin_nontemporal_load(col + sg + 24 + t);
            if (28 + t < dg) mc7 = __builtin_nontemporal_load(col + sg + 28 + t);
#pragma unroll
            for (int j = 0; j < 4; ++j) GATH2(mc6, j)
#pragma unroll
            for (int j = 0; j < 4; ++j) GATH2(mc7, j)
        }
        for (int u = 32;; ++u) {
            bool act = u < dg;
            if (!__any(act)) break;
            if (act) {
                int s_ = col[sg + u];
                uint2 uu = hw[(long long)s_ * 4 + t];
                p0 += make_float2(bf_lo(uu.x), bf_hi(uu.x));
                p1 += make_float2(bf_lo(uu.y), bf_hi(uu.y));
            }
        }
#undef GATH2

        if (r0 + g < N) {
            fx4 o;
            o.x = bq.x + drg * p0.x;
            o.y = bq.y + drg * p0.y;
            o.z = bq.z + drg * p1.x;
            o.w = bq.w + drg * p1.y;
            fx4* op = (fx4*)(out + (long long)(r0 + g) * 32 + hf * 16 + t * 4);
            __builtin_nontemporal_store(o, op);
        }
    }
}

extern "C" void kernel_launch(void* const* d_in, const int* in_sizes, int n_in,
                              void* d_out, int out_size, void* d_ws, size_t ws_size,
                              hipStream_t stream) {
    const float* x  = (const float*)d_in[0];
    const int*   ei = (const int*)d_in[1];
    const float* W1 = (const float*)d_in[2];
    const float* b1 = (const float*)d_in[3];
    const float* W2 = (const float*)d_in[4];
    const float* b2 = (const float*)d_in[5];
    float* out = (float*)d_out;

    const int N = in_sizes[0] / IN_CH;
    const int E = in_sizes[1] / 2;
    const int* esrc = ei;
    const int* edst = ei + E;

    // workspace layout (4-byte units, regions padded to 16)
    // h1: HALF-2 bf16, half hf = ch 32hf..+31, (N+1) x 64B each (12.8MB total)
    // z (scratch): HALF-2 f16, (N+1) x 64B each (12.8MB)
    // h2: HALF-2 bf16, (N+1) x 32B each (6.4MB) -- aliases h1 region (h1 dead after gather1h)
    int* rowptr   = (int*)d_ws;                          // N+1
    int* cursor   = rowptr + (((N + 1) + 15) & ~15);     // N (deg -> scatter cursor)
    int* bsum     = cursor + ((N + 15) & ~15);           // 64 (block sums, <=49 used)
    unsigned* wsW = (unsigned*)(bsum + 64);              // 4096 W1-frag + 1024 W2-frag dwords
    int* col      = (int*)(wsW + 5120);                  // E
    float* dis    = (float*)(col + ((E + 15) & ~15));    // N
    ushort_t* h1  = (ushort_t*)(dis + ((N + 15) & ~15)); // 2*(N+1)*32 bf16
    unsigned* scratch = (unsigned*)(h1 + (((long long)(N + 1) * 64 + 31) & ~31LL));
    unsigned* z     = scratch;            // 2*(N+1)*16 dwords f16 halves (12.8MB)
    ushort_t* h2    = h1;                 // 2*(N+1)*16 bf16 halves (6.4MB), after h1 dead

    const int B = 256;
    const int DB = (E + EPB - 1) / EPB;                 // 782 edge blocks
    const int SB = (N + 2047) / 2048;                   // 49 scan blocks
    const int NBR16 = (N + 15) >> 4;                    // 16-row units per half
    int bph = (NBR16 + 7) / 8;
    int agg_blocks = ((2 * bph + 7) / 8) * 8;           // r7 formula (1568 @ N=100K)
    if (agg_blocks > 2048) agg_blocks = 2048;

    hipMemsetAsync(cursor, 0, (size_t)N * sizeof(int), stream);

    // ---- direct CSR build: histogram -> scan -> scatter (no pairs round-trip) ----
    k_deg<<<DB + 5, B, 0, stream>>>(edst, cursor, E, DB, W1, W2, wsW);
    k_scanA<<<SB, B, 0, stream>>>(cursor, bsum, N);
    k_scanB<<<SB, B, 0, stream>>>(cursor, bsum, rowptr, dis, (unsigned*)h1, N, E);
    k_scatter<<<DB, B, 0, stream>>>(esrc, edst, cursor, col, E);

    k_mm1<<<(N + 63) / 64, B, 0, stream>>>(x, wsW, dis, h1, N);

    // layer-1 aggregation: channel-halves, XCD-quad affinity
    k_gather1h<<<agg_blocks, B, 0, stream>>>((const unsigned*)h1, rowptr, col, dis, b1, z, N);

    // layer-2 transform (MFMA), writes h2 halves over dead h1
    k_mm2<<<(N + 63) / 64, B, 0, stream>>>(z, wsW + 4096, dis, h2, N);

    // final aggregation: channel-halves, L2-resident h2
    k_agg32h<<<agg_blocks, B, 0, stream>>>((const unsigned*)h2, rowptr, col, dis, b2, out, N);
}

// Round 11
// 232.712 us; speedup vs baseline: 1.7467x; 1.7467x over previous
//
#include <hip/hip_runtime.h>
#include <hip/hip_bf16.h>

#define IN_CH 128
#define HID_CH 64
#define OUT_CH 32
#define EPB 2048  // edges per partition block
#define MAXB 512  // max buckets (N <= 131072)

typedef unsigned short ushort_t;
typedef __attribute__((ext_vector_type(8))) short short8;
typedef __attribute__((ext_vector_type(4))) float float4v;
typedef __attribute__((ext_vector_type(4))) float fx4;
typedef __attribute__((ext_vector_type(4))) unsigned ux4;
using half8 = __attribute__((ext_vector_type(8))) _Float16;

static __device__ __forceinline__ ushort_t f2bf(float f) {
    unsigned u = __float_as_uint(f);
    unsigned r = (u + 0x7fff + ((u >> 16) & 1)) >> 16;  // RNE
    return (ushort_t)r;
}
static __device__ __forceinline__ float bf_lo(unsigned u) { return __uint_as_float(u << 16); }
static __device__ __forceinline__ float bf_hi(unsigned u) { return __uint_as_float(u & 0xffff0000u); }

static __device__ __forceinline__ unsigned f2h2(float lo, float hi) {  // RNE f32->f16 pair, packed
    union { _Float16 h[2]; unsigned u; } v;
    v.h[0] = (_Float16)lo;
    v.h[1] = (_Float16)hi;
    return v.u;
}
static __device__ __forceinline__ unsigned pkh(float a, float b) {  // RTZ packed cvt (fast path)
    auto p = __builtin_amdgcn_cvt_pkrtz(a, b);
    union { decltype(p) h; unsigned u; } v;
    v.h = p;
    return v.u;
}

// ---------------- radix partition by dst>>8 (+ prepW in 5 trailing blocks) ----------------
// (r10 lesson: the pairs round-trip is what makes the CSR scatter L2-local; direct scatter
// was 155us from 16x write amplification + atomic-return serialization.)

__global__ __launch_bounds__(256) void k_partition(const int* __restrict__ src,
                                                   const int* __restrict__ dst,
                                                   int* __restrict__ gcursor,
                                                   unsigned* __restrict__ pairs,
                                                   int E, int nbk, int cap, int PB,
                                                   const float* __restrict__ W1,
                                                   const float* __restrict__ W2,
                                                   unsigned* __restrict__ wsW) {
    __shared__ int lhist[MAXB];
    __shared__ int lbase[MAXB];
    __shared__ int lcur[MAXB];
    const int tid = threadIdx.x;

    if (blockIdx.x >= PB) {  // prepW blocks
        int s = (blockIdx.x - PB) * 256 + tid;  // 0..1279
        if (s < 1024) {                          // W1 -> bf16 b-frags
            int lane = s & 63;
            int nt = (s >> 6) & 3;
            int kc = s >> 8;
            int c = nt * 16 + (lane & 15);
            int k0 = kc * 32 + (lane >> 4) * 8;
            unsigned o[4];
#pragma unroll
            for (int d = 0; d < 4; ++d) {
                unsigned lo = f2bf(W1[(k0 + 2 * d) * 64 + c]);
                unsigned hi = f2bf(W1[(k0 + 2 * d + 1) * 64 + c]);
                o[d] = lo | (hi << 16);
            }
            ((uint4*)wsW)[s] = make_uint4(o[0], o[1], o[2], o[3]);
        } else {  // W2 -> f16 b-frags: frag f = kt*2+ct
            int q = s - 1024;  // 0..255
            int lane = q & 63;
            int f = q >> 6;
            int c = (f & 1) * 16 + (lane & 15);
            int k0 = (f >> 1) * 32 + (lane >> 4) * 8;
            unsigned o[4];
#pragma unroll
            for (int d = 0; d < 4; ++d)
                o[d] = f2h2(W2[(k0 + 2 * d) * 32 + c], W2[(k0 + 2 * d + 1) * 32 + c]);
            ((uint4*)wsW)[1024 + q] = make_uint4(o[0], o[1], o[2], o[3]);
        }
        return;
    }

    for (int b = tid; b < nbk; b += 256) { lhist[b] = 0; lcur[b] = 0; }
    __syncthreads();
    int s[8], d[8];
    const int e0 = blockIdx.x * EPB;
#pragma unroll
    for (int j = 0; j < 8; ++j) {
        int e = e0 + j * 256 + tid;
        if (e < E) {
            s[j] = src[e];
            d[j] = dst[e];
            atomicAdd(&lhist[d[j] >> 8], 1);
        } else {
            d[j] = -1;
        }
    }
    __syncthreads();
    for (int b = tid; b < nbk; b += 256)
        lbase[b] = lhist[b] ? atomicAdd(&gcursor[b], lhist[b]) : 0;
    __syncthreads();
#pragma unroll
    for (int j = 0; j < 8; ++j) {
        if (d[j] >= 0) {
            int b = d[j] >> 8;
            int loc = atomicAdd(&lcur[b], 1);
            int idx = lbase[b] + loc;
            if (idx < cap)
                pairs[(long long)b * cap + idx] = ((unsigned)s[j] << 8) | (unsigned)(d[j] & 255);
        }
    }
}

// ---------------- fused per-bucket build (inline bucket-total scan) ----------------
// Also zeroes the h1 HALF pad rows (2 halves x 64B) used by gather pad lanes.

__global__ __launch_bounds__(256) void k_bucket_build(const unsigned* __restrict__ pairs,
                                                      const int* __restrict__ gcursor,
                                                      int* __restrict__ rowptr,
                                                      int* __restrict__ col,
                                                      float* __restrict__ dis,
                                                      unsigned* __restrict__ h1d,
                                                      int cap, int N) {
    __shared__ int lc[256];
    __shared__ int ls[256];
    __shared__ int lcur[256];
    const int b = blockIdx.x, tid = threadIdx.x;

    if (b == 0 && tid < 32)  // half hf pad row: 32 bf16 = 16 dwords
        h1d[(long long)(tid >> 4) * (N + 1) * 16 + (long long)N * 16 + (tid & 15)] = 0;

    int ga = min(gcursor[2 * tid], cap);
    int gb = min(gcursor[2 * tid + 1], cap);
    ls[tid] = ga + gb;
    __syncthreads();
    for (int off = 1; off < 256; off <<= 1) {
        int val = (tid >= off) ? ls[tid - off] : 0;
        __syncthreads();
        ls[tid] += val;
        __syncthreads();
    }
    const int p = b >> 1;
    const int base = (p ? ls[p - 1] : 0) + ((b & 1) ? min(gcursor[b - 1], cap) : 0);
    const int total = ls[255];
    __syncthreads();
    if (b == 0 && tid == 0) rowptr[N] = total;

    lc[tid] = 0;
    __syncthreads();
    const int cnt = min(gcursor[b], cap);
    const unsigned* pp = pairs + (long long)b * cap;
    for (int i = tid; i < cnt; i += 256) atomicAdd(&lc[pp[i] & 255], 1);
    __syncthreads();
    const int v = lc[tid];
    ls[tid] = v;
    __syncthreads();
    for (int off = 1; off < 256; off <<= 1) {
        int val = (tid >= off) ? ls[tid - off] : 0;
        __syncthreads();
        ls[tid] += val;
        __syncthreads();
    }
    const int excl = ls[tid] - v;
    const int row = b * 256 + tid;
    if (row < N) {
        rowptr[row] = base + excl;
        dis[row] = rsqrtf((float)(v + 1));  // +1 self-loop
    }
    lcur[tid] = base + excl;
    __syncthreads();
    for (int i = tid; i < cnt; i += 256) {
        unsigned pk = pp[i];
        int pos = atomicAdd(&lcur[pk & 255], 1);
        col[pos] = (int)(pk >> 8);
    }
}

// ---------------- L1 matmul via MFMA; HALF-2 output: half hf = channels 32hf..32hf+31 ----------------
// h1'[hf][row][32ch bf16 = 64B = one cache line], pre-scaled by dis[row].

__global__ __launch_bounds__(256) void k_mm1(const float* __restrict__ X,
                                             const unsigned* __restrict__ wsW,
                                             const float* __restrict__ dis,
                                             ushort_t* __restrict__ H, int N) {
    const int tid = threadIdx.x;
    const int wv = tid >> 6, lane = tid & 63;
    const int quad = lane >> 4, n16 = lane & 15;
    const int rowbase = blockIdx.x * 64 + wv * 16;
    const int myrow = rowbase + n16;
    const bool rok = (myrow < N);

    float4v acc0 = {}, acc1 = {}, acc2 = {}, acc3 = {};

#pragma unroll
    for (int kc = 0; kc < 4; ++kc) {
        float4 xa = make_float4(0.f, 0.f, 0.f, 0.f), xb = xa;
        if (rok) {
            const float4* p = (const float4*)(X + (long long)myrow * 128 + kc * 32 + quad * 8);
            xa = p[0];
            xb = p[1];
        }
        unsigned pk[4];
        pk[0] = (unsigned)f2bf(xa.x) | ((unsigned)f2bf(xa.y) << 16);
        pk[1] = (unsigned)f2bf(xa.z) | ((unsigned)f2bf(xa.w) << 16);
        pk[2] = (unsigned)f2bf(xb.x) | ((unsigned)f2bf(xb.y) << 16);
        pk[3] = (unsigned)f2bf(xb.z) | ((unsigned)f2bf(xb.w) << 16);
        short8 a;
        a[0] = (short)(pk[0] & 0xffff); a[1] = (short)(pk[0] >> 16);
        a[2] = (short)(pk[1] & 0xffff); a[3] = (short)(pk[1] >> 16);
        a[4] = (short)(pk[2] & 0xffff); a[5] = (short)(pk[2] >> 16);
        a[6] = (short)(pk[3] & 0xffff); a[7] = (short)(pk[3] >> 16);

        const short8* wb = (const short8*)wsW;
        short8 b0 = wb[(kc * 4 + 0) * 64 + lane];
        short8 b1 = wb[(kc * 4 + 1) * 64 + lane];
        short8 b2 = wb[(kc * 4 + 2) * 64 + lane];
        short8 b3 = wb[(kc * 4 + 3) * 64 + lane];

        acc0 = __builtin_amdgcn_mfma_f32_16x16x32_bf16(a, b0, acc0, 0, 0, 0);
        acc1 = __builtin_amdgcn_mfma_f32_16x16x32_bf16(a, b1, acc1, 0, 0, 0);
        acc2 = __builtin_amdgcn_mfma_f32_16x16x32_bf16(a, b2, acc2, 0, 0, 0);
        acc3 = __builtin_amdgcn_mfma_f32_16x16x32_bf16(a, b3, acc3, 0, 0, 0);
    }

    const long long hb1 = (long long)(N + 1) * 32;  // half-1 base (ushort units)
#pragma unroll
    for (int i = 0; i < 4; ++i) {
        int row = rowbase + quad * 4 + i;
        if (row < N) {
            float dr = dis[row];
            long long o = (long long)row * 32 + n16;
            H[o]            = f2bf(dr * acc0[i]);  // ch n16       (half 0)
            H[o + 16]       = f2bf(dr * acc1[i]);  // ch 16+n16    (half 0)
            H[hb1 + o]      = f2bf(dr * acc2[i]);  // ch 32+n16    (half 1)
            H[hb1 + o + 16] = f2bf(dr * acc3[i]);  // ch 48+n16    (half 1)
        }
    }
}

// ---------------- gather1h: layer-1 aggregation, channel-HALF per XCD-quad (r7, verified) ----------------

__global__ __launch_bounds__(256, 8) void k_gather1h(const unsigned* __restrict__ h,
                                                     const int* __restrict__ rowptr,
                                                     const int* __restrict__ col,
                                                     const float* __restrict__ dis,
                                                     const float* __restrict__ b1,
                                                     unsigned* __restrict__ z, int N) {
    const int tid = threadIdx.x;
    const int wv = tid >> 6, lane = tid & 63;
    const int t = lane & 3, g = lane >> 2;  // 16 groups x 4 lanes
    const int xcd = blockIdx.x & 7;
    const int hf = xcd >> 2;
    const int pb = ((blockIdx.x >> 3) << 2) | (xcd & 3);  // per-half block id
    const int nwh = ((gridDim.x >> 3) << 2) * 4;          // waves per half

    const uint4* h4 = (const uint4*)h + (long long)hf * (N + 1) * 4;  // 64B rows
    ux4* zp = (ux4*)z + (long long)hf * (N + 1) * 4;
    const float4 ba = ((const float4*)b1)[hf * 8 + t * 2];      // ch 32hf+8t..+3
    const float4 bb = ((const float4*)b1)[hf * 8 + t * 2 + 1];  // ch 32hf+8t+4..+7

    const int NBR = (N + 15) >> 4;

    for (int ri = pb * 4 + wv; ri < NBR; ri += nwh) {
        const int r0 = ri * 16;
        int rp_l = rowptr[min(r0 + min(lane, 16), N)];
        float dis_l = (lane < 16 && r0 + lane < N) ? dis[r0 + lane] : 0.f;
        const int sg = __shfl(rp_l, g);
        const int dg = __shfl(rp_l, g + 1) - sg;
        const float drg = __shfl(dis_l, g);
        const int rme = min(r0 + g, N);

        int mc0 = N, mc1 = N, mc2 = N, mc3 = N, mc4 = N, mc5 = N;
        if (t < dg)      mc0 = __builtin_nontemporal_load(col + sg + t);
        if (4 + t < dg)  mc1 = __builtin_nontemporal_load(col + sg + 4 + t);
        if (8 + t < dg)  mc2 = __builtin_nontemporal_load(col + sg + 8 + t);
        if (12 + t < dg) mc3 = __builtin_nontemporal_load(col + sg + 12 + t);
        if (16 + t < dg) mc4 = __builtin_nontemporal_load(col + sg + 16 + t);
        if (20 + t < dg) mc5 = __builtin_nontemporal_load(col + sg + 20 + t);

        uint4 us = h4[(long long)rme * 4 + t];  // self-loop slice (pre-scaled)
        float2 p0 = make_float2(bf_lo(us.x), bf_hi(us.x));
        float2 p1 = make_float2(bf_lo(us.y), bf_hi(us.y));
        float2 p2 = make_float2(bf_lo(us.z), bf_hi(us.z));
        float2 p3 = make_float2(bf_lo(us.w), bf_hi(us.w));

#define GATH(MC, J)                                                   \
    {                                                                 \
        int s_ = __shfl((MC), (g << 2) + (J));                        \
        uint4 uu = h4[(long long)s_ * 4 + t];                         \
        p0 += make_float2(bf_lo(uu.x), bf_hi(uu.x));                  \
        p1 += make_float2(bf_lo(uu.y), bf_hi(uu.y));                  \
        p2 += make_float2(bf_lo(uu.z), bf_hi(uu.z));                  \
        p3 += make_float2(bf_lo(uu.w), bf_hi(uu.w));                  \
    }
#pragma unroll
        for (int j = 0; j < 4; ++j) GATH(mc0, j)
#pragma unroll
        for (int j = 0; j < 4; ++j) GATH(mc1, j)
#pragma unroll
        for (int j = 0; j < 4; ++j) GATH(mc2, j)
#pragma unroll
        for (int j = 0; j < 4; ++j) GATH(mc3, j)
#pragma unroll
        for (int j = 0; j < 4; ++j) GATH(mc4, j)
#pragma unroll
        for (int j = 0; j < 4; ++j) GATH(mc5, j)
        if (__any(dg > 24)) {
            int mc6 = N, mc7 = N;
            if (24 + t < dg) mc6 = __builtin_nontemporal_load(col + sg + 24 + t);
            if (28 + t < dg) mc7 = __builtin_nontemporal_load(col + sg + 28 + t);
#pragma unroll
            for (int j = 0; j < 4; ++j) GATH(mc6, j)
#pragma unroll
            for (int j = 0; j < 4; ++j) GATH(mc7, j)
        }
        for (int u = 32;; ++u) {  // ultra-rare serial tail (broadcast col within group)
            bool act = u < dg;
            if (!__any(act)) break;
            if (act) {
                int s_ = col[sg + u];
                uint4 uu = h4[(long long)s_ * 4 + t];
                p0 += make_float2(bf_lo(uu.x), bf_hi(uu.x));
                p1 += make_float2(bf_lo(uu.y), bf_hi(uu.y));
                p2 += make_float2(bf_lo(uu.z), bf_hi(uu.z));
                p3 += make_float2(bf_lo(uu.w), bf_hi(uu.w));
            }
        }
#undef GATH

        if (r0 + g < N) {
            float z0 = fmaxf(fmaf(drg, p0.x, ba.x), 0.f);
            float z1 = fmaxf(fmaf(drg, p0.y, ba.y), 0.f);
            float z2 = fmaxf(fmaf(drg, p1.x, ba.z), 0.f);
            float z3 = fmaxf(fmaf(drg, p1.y, ba.w), 0.f);
            float z4 = fmaxf(fmaf(drg, p2.x, bb.x), 0.f);
            float z5 = fmaxf(fmaf(drg, p2.y, bb.y), 0.f);
            float z6 = fmaxf(fmaf(drg, p3.x, bb.z), 0.f);
            float z7 = fmaxf(fmaf(drg, p3.y, bb.w), 0.f);
            ux4 zo;
            zo.x = pkh(z0, z1);
            zo.y = pkh(z2, z3);
            zo.z = pkh(z4, z5);
            zo.w = pkh(z6, z7);
            __builtin_nontemporal_store(zo, zp + (long long)(r0 + g) * 4 + t);
        }
    }
}

// ---------------- mm2: h2' = dis[row]*(z @ W2); z from 2 f16 halves; h2 ROW-MAJOR bf16 ----------------
// h2[row][32ch bf16] = 64B = ONE cache line per row -> agg32 gathers 1 line/edge (touch model).
// Also zeroes the h2 pad row (64B).

__global__ __launch_bounds__(256) void k_mm2(const unsigned* __restrict__ z,
                                             const unsigned* __restrict__ wsW2,
                                             const float* __restrict__ dis,
                                             ushort_t* __restrict__ H2, int N) {
    const int tid = threadIdx.x;
    if (blockIdx.x == 0 && tid < 16)
        ((unsigned*)H2)[(long long)N * 16 + tid] = 0;  // pad row (32 bf16 = 16 dwords)

    const int wv = tid >> 6, lane = tid & 63;
    const int n16 = lane & 15, kq = lane >> 4;
    const int rowbase = blockIdx.x * 64 + wv * 16;
    const int rz = min(rowbase + n16, N - 1);

    const uint4* z4 = (const uint4*)z;
    uint4 a0 = z4[(long long)rz * 4 + kq];                          // half0: ch 8kq..+7
    uint4 a1 = z4[(long long)(N + 1) * 4 + (long long)rz * 4 + kq]; // half1: ch 32+8kq..+7

    const half8* wfh = (const half8*)wsW2;
    const half8 bf00 = wfh[lane];
    const half8 bf01 = wfh[64 + lane];
    const half8 bf10 = wfh[128 + lane];
    const half8 bf11 = wfh[192 + lane];

    union U { uint4 u; half8 h; };
    U ua0, ua1;
    ua0.u = a0;
    ua1.u = a1;

    float4v c0 = {}, c1 = {};
    c0 = __builtin_amdgcn_mfma_f32_16x16x32_f16(ua0.h, bf00, c0, 0, 0, 0);
    c0 = __builtin_amdgcn_mfma_f32_16x16x32_f16(ua1.h, bf10, c0, 0, 0, 0);
    c1 = __builtin_amdgcn_mfma_f32_16x16x32_f16(ua0.h, bf01, c1, 0, 0, 0);
    c1 = __builtin_amdgcn_mfma_f32_16x16x32_f16(ua1.h, bf11, c1, 0, 0, 0);

    float dis_l = (lane < 16 && rowbase + lane < N) ? dis[rowbase + lane] : 0.f;
#pragma unroll
    for (int i = 0; i < 4; ++i) {
        int rr = rowbase + kq * 4 + i;  // C row = (lane>>4)*4 + reg
        float dr = __shfl(dis_l, kq * 4 + i);
        if (rr < N) {
            H2[(long long)rr * 32 + n16]      = f2bf(dr * c0[i]);  // ch n16
            H2[(long long)rr * 32 + 16 + n16] = f2bf(dr * c1[i]);  // ch 16+n16
        }
    }
}

// ---------------- agg32: final aggregation, UNSPLIT h2 (r3-verified), 8-lane row-groups ----------------
// h2 row = 64B = one line -> 1.6M line-touches (vs 3.2M half-split). 8 rows/wave, no reduce.

__global__ __launch_bounds__(256, 8) void k_agg32(const unsigned* __restrict__ h,
                                                  const int* __restrict__ rowptr,
                                                  const int* __restrict__ col,
                                                  const float* __restrict__ dis,
                                                  const float* __restrict__ b,
                                                  float* __restrict__ out, int N) {
    const int tid = threadIdx.x;
    const int wv = tid >> 6, lane = tid & 63;
    const int t = lane & 7, g = lane >> 3;
    const float4 bq = ((const float4*)b)[t];  // channels 4t..4t+3
    const uint2* hw = (const uint2*)h;
    const int NB = (N + 7) >> 3;
    const int step = gridDim.x * 4;

    for (int rb = blockIdx.x * 4 + wv; rb < NB; rb += step) {
        const int r0 = rb * 8;
        int rp_l = rowptr[min(r0 + min(lane, 8), N)];
        float dis_l = (lane < 8 && r0 + lane < N) ? dis[r0 + lane] : 0.f;
        const int sg = __shfl(rp_l, g);
        const int dg = __shfl(rp_l, g + 1) - sg;
        const float drg = __shfl(dis_l, g);

        int mc1 = N, mc2 = N, mc3 = N;
        if (t < dg)      mc1 = __builtin_nontemporal_load(col + sg + t);
        if (8 + t < dg)  mc2 = __builtin_nontemporal_load(col + sg + 8 + t);
        if (16 + t < dg) mc3 = __builtin_nontemporal_load(col + sg + 16 + t);

        const int rme = min(r0 + g, N);
        uint2 us = hw[(long long)rme * 8 + t];  // self-loop slice
        float2 p0 = make_float2(bf_lo(us.x), bf_hi(us.x));
        float2 p1 = make_float2(bf_lo(us.y), bf_hi(us.y));

#define GAT2(MC, U)                                                   \
    {                                                                 \
        int s_ = __shfl((MC), (g << 3) + (U));                        \
        uint2 uu = hw[(long long)s_ * 8 + t];                         \
        p0 += make_float2(bf_lo(uu.x), bf_hi(uu.x));                  \
        p1 += make_float2(bf_lo(uu.y), bf_hi(uu.y));                  \
    }
#pragma unroll
        for (int u = 0; u < 8; ++u) GAT2(mc1, u)
#pragma unroll
        for (int u = 0; u < 8; ++u) GAT2(mc2, u)
#pragma unroll
        for (int u = 0; u < 8; ++u) GAT2(mc3, u)
        if (__any(dg > 24)) {
            int mc4 = N;
            if (24 + t < dg) mc4 = __builtin_nontemporal_load(col + sg + 24 + t);
#pragma unroll
            for (int u = 0; u < 8; ++u) GAT2(mc4, u)
        }
        for (int u = 32; u < dg; ++u) {  // ultra-rare serial tail (broadcast col)
            int s_ = col[sg + u];
            uint2 uu = hw[(long long)s_ * 8 + t];
            p0 += make_float2(bf_lo(uu.x), bf_hi(uu.x));
            p1 += make_float2(bf_lo(uu.y), bf_hi(uu.y));
        }
#undef GAT2

        const int rr = r0 + g;
        if (rr < N) {
            fx4 o;
            o.x = bq.x + drg * p0.x;
            o.y = bq.y + drg * p0.y;
            o.z = bq.z + drg * p1.x;
            o.w = bq.w + drg * p1.y;
            __builtin_nontemporal_store(o, (fx4*)(out + (long long)rr * 32 + t * 4));
        }
    }
}

extern "C" void kernel_launch(void* const* d_in, const int* in_sizes, int n_in,
                              void* d_out, int out_size, void* d_ws, size_t ws_size,
                              hipStream_t stream) {
    const float* x  = (const float*)d_in[0];
    const int*   ei = (const int*)d_in[1];
    const float* W1 = (const float*)d_in[2];
    const float* b1 = (const float*)d_in[3];
    const float* W2 = (const float*)d_in[4];
    const float* b2 = (const float*)d_in[5];
    float* out = (float*)d_out;

    const int N = in_sizes[0] / IN_CH;
    const int E = in_sizes[1] / 2;
    const int* esrc = ei;
    const int* edst = ei + E;

    int nbk = (N + 255) >> 8;
    if (nbk > MAXB) nbk = MAXB;
    const int per_b = (E + nbk - 1) / nbk;
    const int cap = per_b + per_b / 4 + 256;  // ~20-sigma headroom

    // workspace layout (4-byte units, regions padded to 16)
    // h1: HALF-2 bf16, half hf = ch 32hf..+31, (N+1) x 64B each (12.8MB total)
    // z (scratch, pairs dead): HALF-2 f16, (N+1) x 64B each (12.8MB)
    // h2: ROW-MAJOR bf16, (N+1) x 64B (6.4MB) -- aliases h1 region (h1 dead after gather1h)
    int* rowptr   = (int*)d_ws;                          // N+1
    int* gcursor  = rowptr + (((N + 1) + 15) & ~15);     // MAXB
    unsigned* wsW = (unsigned*)(gcursor + MAXB);         // 4096 W1-frag + 1024 W2-frag dwords
    int* col      = (int*)(wsW + 5120);                  // E
    float* dis    = (float*)(col + ((E + 15) & ~15));    // N
    ushort_t* h1  = (ushort_t*)(dis + ((N + 15) & ~15)); // 2*(N+1)*32 bf16
    unsigned* scratch = (unsigned*)(h1 + (((long long)(N + 1) * 64 + 31) & ~31LL));
    unsigned* pairs = scratch;            // nbk*cap dwords (~8.4MB), dead after bucket_build
    unsigned* z     = scratch;            // 2*(N+1)*16 dwords f16 halves (12.8MB)
    ushort_t* h2    = h1;                 // (N+1)*32 bf16 row-major (6.4MB), after h1 dead

    const int B = 256;
    const int PB = (E + EPB - 1) / EPB;
    const int NBR16 = (N + 15) >> 4;                    // 16-row units per half (gather1h)
    int bph = (NBR16 + 7) / 8;
    int g1_blocks = ((2 * bph + 7) / 8) * 8;            // r7 formula (1568 @ N=100K)
    if (g1_blocks > 2048) g1_blocks = 2048;

    hipMemsetAsync(gcursor, 0, MAXB * sizeof(int), stream);
    k_partition<<<PB + 5, B, 0, stream>>>(esrc, edst, gcursor, pairs, E, nbk, cap, PB, W1, W2, wsW);
    k_bucket_build<<<nbk, B, 0, stream>>>(pairs, gcursor, rowptr, col, dis, (unsigned*)h1, cap, N);

    k_mm1<<<(N + 63) / 64, B, 0, stream>>>(x, wsW, dis, h1, N);

    // layer-1 aggregation: channel-halves, XCD-quad affinity
    k_gather1h<<<g1_blocks, B, 0, stream>>>((const unsigned*)h1, rowptr, col, dis, b1, z, N);

    // layer-2 transform (MFMA), writes row-major h2 over dead h1
    k_mm2<<<(N + 63) / 64, B, 0, stream>>>(z, wsW + 4096, dis, h2, N);

    // final aggregation: unsplit h2, one line per edge (half the line-touches of half-split)
    k_agg32<<<2048, B, 0, stream>>>((const unsigned*)h2, rowptr, col, dis, b2, out, N);
}